// Round 1
// baseline (300.530 us; speedup 1.0000x reference)
//
#include <hip/hip_runtime.h>
#include <hip/hip_bf16.h>
#include <cstdint>
#include <cstddef>

#define D_MODEL 1024
#define SEQ     2048
#define BATCH   8
#define M_TOT   (BATCH*SEQ)     // 16384
#define N_TOT   (3*D_MODEL)     // 3072
#define K_TOT   D_MODEL         // 1024
#define NC      16              // scan chunks
#define LC      (SEQ/NC)        // 128

typedef unsigned short u16;
typedef __attribute__((ext_vector_type(8))) short short8;
typedef __attribute__((ext_vector_type(4))) float f32x4;

__device__ __forceinline__ u16 f2bf(float f) {
    __hip_bfloat16 h = __float2bfloat16(f);   // RNE
    return __builtin_bit_cast(u16, h);
}
__device__ __forceinline__ float bf2f(u16 u) {
    __hip_bfloat16 h = __builtin_bit_cast(__hip_bfloat16, u);
    return __bfloat162float(h);
}
__device__ __forceinline__ float sigmoidf(float v) {
    return 1.0f / (1.0f + __expf(-v));
}
__device__ __forceinline__ void gld_lds16(const void* g, void* l) {
    __builtin_amdgcn_global_load_lds((const __attribute__((address_space(1))) void*)g,
                                     (__attribute__((address_space(3))) void*)l, 16, 0, 0);
}

// ---------------------------------------------------------------------------
// x (fp32) -> xb (bf16), fused with column-sum over L for the SToken mean.
// grid: 8 b * 4 dblk * 16 tblk = 512 blocks, 256 thr
__global__ void k_convert_x(const float* __restrict__ x, u16* __restrict__ xb,
                            float* __restrict__ sq) {
    int bid  = blockIdx.x;
    int tblk = bid & 15, dblk = (bid >> 4) & 3, b = bid >> 6;
    int d = dblk * 256 + threadIdx.x;
    size_t base = ((size_t)b * SEQ + (size_t)tblk * LC) * D_MODEL + d;
    float sum = 0.f;
    for (int t = 0; t < LC; ++t) {
        float v = x[base + (size_t)t * D_MODEL];
        sum += v;
        xb[base + (size_t)t * D_MODEL] = f2bf(v);
    }
    atomicAdd(&sq[b * D_MODEL + d], sum);
}

// W_B, W_C, W_d (fp32 [1024,1024]) -> wcat (bf16 [3072,1024])
// grid: 3072 blocks * 256 thr, 4 elems/thread
__global__ void k_convert_w(const float* __restrict__ WB, const float* __restrict__ WC,
                            const float* __restrict__ Wd, u16* __restrict__ wcat) {
    int tg = blockIdx.x * 256 + threadIdx.x;
    size_t e0 = (size_t)tg * 4;
    int n = (int)(e0 >> 10), k0 = (int)(e0 & 1023);
    const float* W = (n < 1024) ? (WB + (size_t)n * 1024)
                   : (n < 2048) ? (WC + (size_t)(n - 1024) * 1024)
                                : (Wd + (size_t)(n - 2048) * 1024);
    float4 v = *(const float4*)&W[k0];
    wcat[e0 + 0] = f2bf(v.x);
    wcat[e0 + 1] = f2bf(v.y);
    wcat[e0 + 2] = f2bf(v.z);
    wcat[e0 + 3] = f2bf(v.w);
}

// stv[b,n] = sigmoid(relu( (sq[b,:]/L) @ W_st[n,:] + b_st[n] ))
// grid: 8 b * 4 nblk = 32 blocks, 256 thr
__global__ void k_stoken(const float* __restrict__ sq, const float* __restrict__ Wst,
                         const float* __restrict__ bst, float* __restrict__ stv) {
    __shared__ float s[D_MODEL];
    int b = blockIdx.x >> 2, nblk = blockIdx.x & 3;
    for (int i = threadIdx.x; i < D_MODEL; i += 256)
        s[i] = sq[b * D_MODEL + i] * (1.0f / SEQ);
    __syncthreads();
    int n = nblk * 256 + threadIdx.x;
    const float* w = Wst + (size_t)n * D_MODEL;
    float acc = 0.f;
    for (int k = 0; k < D_MODEL; k += 4) {
        float4 wv = *(const float4*)&w[k];
        acc += s[k] * wv.x + s[k+1] * wv.y + s[k+2] * wv.z + s[k+3] * wv.w;
    }
    acc += bst[n];
    acc = fmaxf(acc, 0.f);
    stv[b * D_MODEL + n] = sigmoidf(acc);
}

// ---------------------------------------------------------------------------
// bf16 GEMM, B^T form: Cout[i,n] = sum_k A[i,k] * Bm[n,k].  m97 structure:
// 128x128 tile, BK=32, 4 waves (2x2), global_load_lds width 16, 2 barriers.
__global__ __launch_bounds__(256) void k_gemm(const u16* __restrict__ A,
                                              const u16* __restrict__ Bm,
                                              u16* __restrict__ Cout) {
    __shared__ u16 lsA[128 * 32];
    __shared__ u16 lsB[128 * 32];
    const int tid = threadIdx.x;
    const int lane = tid & 63, wave = tid >> 6;
    const int wM = wave >> 1, wN = wave & 1;
    const int i0 = blockIdx.y * 128;
    const int n0 = blockIdx.x * 128;
    const int r = lane & 15, g = lane >> 4;

    f32x4 acc[4][4] = {};

    for (int k0 = 0; k0 < K_TOT; k0 += 32) {
        // stage A and B tiles: 8KB each, 2 passes of (256 thr * 16B) per tile
#pragma unroll
        for (int p = 0; p < 2; ++p) {
            int offBase = p * 4096 + wave * 1024;     // wave-uniform LDS byte base
            int off = offBase + lane * 16;            // this lane's slot
            int row = off >> 6;                       // 64 B per tile row (32 bf16)
            int cole = (off & 63) >> 1;               // element offset in row
            gld_lds16(A + (size_t)(i0 + row) * K_TOT + k0 + cole, (char*)lsA + offBase);
            gld_lds16(Bm + (size_t)(n0 + row) * K_TOT + k0 + cole, (char*)lsB + offBase);
        }
        __syncthreads();   // compiler drains vmcnt(0) before barrier -> LDS valid

        short8 af[4], bfr[4];
#pragma unroll
        for (int m = 0; m < 4; ++m)
            af[m] = *(const short8*)&lsA[(wM * 64 + m * 16 + r) * 32 + g * 8];
#pragma unroll
        for (int n = 0; n < 4; ++n)
            bfr[n] = *(const short8*)&lsB[(wN * 64 + n * 16 + r) * 32 + g * 8];
#pragma unroll
        for (int m = 0; m < 4; ++m)
#pragma unroll
            for (int n = 0; n < 4; ++n)
                acc[m][n] = __builtin_amdgcn_mfma_f32_16x16x32_bf16(af[m], bfr[n], acc[m][n], 0, 0, 0);
        __syncthreads();   // all waves done reading before next stage overwrites
    }

    // epilogue: C/D layout col=lane&15, row=(lane>>4)*4+j  [HW-verified]
#pragma unroll
    for (int m = 0; m < 4; ++m)
#pragma unroll
        for (int n = 0; n < 4; ++n)
#pragma unroll
            for (int j = 0; j < 4; ++j) {
                size_t row = (size_t)(i0 + wM * 64 + m * 16 + g * 4 + j);
                size_t col = (size_t)(n0 + wN * 64 + n * 16 + r);
                Cout[row * N_TOT + col] = f2bf(acc[m][n][j]);
            }
}

// ---------------------------------------------------------------------------
// Chunked scan. PHASE 1: local scan (s0=0), store P=prod(a), sEnd.
// PHASE 2: replay with exact carry-in, emit output.
// grid: 8 b * 16 chunk * 4 dblk = 512 blocks, 256 thr
template <int PHASE>
__global__ void k_scan(const float* __restrict__ x, const u16* __restrict__ g3,
                       const float* __restrict__ dp, const float* __restrict__ Aar,
                       const float* __restrict__ bB, const float* __restrict__ bC,
                       const float* __restrict__ bd, const float* __restrict__ stv,
                       const float* __restrict__ stb, const float* __restrict__ cin,
                       float* __restrict__ Pout, float* __restrict__ sEnd,
                       float* __restrict__ out) {
    int bid = blockIdx.x;
    int dblk = bid & 3, c = (bid >> 2) & (NC - 1), b = bid >> 6;
    int d = dblk * 256 + threadIdx.x;

    float bBv = bB[d], bdv = bd[d];
    float s = (PHASE == 1) ? 0.f : cin[(b * NC + c) * D_MODEL + d];
    float P = 1.f;
    float bCv = 0.f, tc = 0.f;
    if (PHASE == 2) { bCv = bC[d]; tc = stv[b * D_MODEL + d] + stb[d]; }

    int t0 = c * LC;
    size_t xoff = ((size_t)b * SEQ + t0) * D_MODEL + d;
    size_t goff = ((size_t)b * SEQ + t0) * N_TOT + d;
    size_t poff = (size_t)t0 * D_MODEL + d;

    for (int t = 0; t < LC; ++t) {
        float xv = x[xoff];
        float b0 = bf2f(g3[goff]) + bBv;
        float dl = bf2f(g3[goff + 2048]) + bdv + dp[poff];
        float delta = sigmoidf(dl);
        float a = delta * Aar[poff];
        s = a * s + delta * b0 * xv;
        if (PHASE == 1) P *= a;
        if (PHASE == 2) {
            float cv = bf2f(g3[goff + 1024]) + bCv;
            float y = cv * s + tc * xv;
            out[xoff] = y * sigmoidf(xv);
        }
        xoff += D_MODEL; goff += N_TOT; poff += D_MODEL;
    }
    if (PHASE == 1) {
        Pout[(size_t)(b * NC + c) * D_MODEL + d] = P;
        sEnd[(size_t)(b * NC + c) * D_MODEL + d] = s;
    }
}

// carry_in[c] = P[c-1]*carry_in[c-1] + sEnd[c-1]  (exact affine combine)
__global__ void k_combine(const float* __restrict__ P, const float* __restrict__ sEnd,
                          float* __restrict__ cin) {
    int idx = blockIdx.x * 256 + threadIdx.x;   // 8192
    int b = idx >> 10, d = idx & 1023;
    float carry = 0.f;
    for (int c = 0; c < NC; ++c) {
        size_t o = (size_t)(b * NC + c) * D_MODEL + d;
        cin[o] = carry;
        carry = P[o] * carry + sEnd[o];
    }
}

// ---------------------------------------------------------------------------
extern "C" void kernel_launch(void* const* d_in, const int* in_sizes, int n_in,
                              void* d_out, int out_size, void* d_ws, size_t ws_size,
                              hipStream_t stream) {
    const float* x    = (const float*)d_in[0];
    const float* W_B  = (const float*)d_in[1];
    const float* b_B  = (const float*)d_in[2];
    const float* W_C  = (const float*)d_in[3];
    const float* b_C  = (const float*)d_in[4];
    const float* W_d  = (const float*)d_in[5];
    const float* b_d  = (const float*)d_in[6];
    const float* dp   = (const float*)d_in[7];
    const float* Aar  = (const float*)d_in[8];
    const float* W_st = (const float*)d_in[9];
    const float* b_st = (const float*)d_in[10];
    const float* stb  = (const float*)d_in[11];
    float* out = (float*)d_out;

    char* ws = (char*)d_ws;
    u16* xb   = (u16*)ws;  ws += (size_t)M_TOT * K_TOT * 2;   // 33.5 MB
    u16* wcat = (u16*)ws;  ws += (size_t)N_TOT * K_TOT * 2;   //  6.3 MB
    u16* g3   = (u16*)ws;  ws += (size_t)M_TOT * N_TOT * 2;   // 100.7 MB
    float* sq   = (float*)ws; ws += (size_t)BATCH * D_MODEL * 4;
    float* stv  = (float*)ws; ws += (size_t)BATCH * D_MODEL * 4;
    float* Pp   = (float*)ws; ws += (size_t)BATCH * NC * D_MODEL * 4;
    float* sEnd = (float*)ws; ws += (size_t)BATCH * NC * D_MODEL * 4;
    float* cin  = (float*)ws; ws += (size_t)BATCH * NC * D_MODEL * 4;

    hipMemsetAsync(sq, 0, (size_t)BATCH * D_MODEL * 4, stream);
    k_convert_x<<<512, 256, 0, stream>>>(x, xb, sq);
    k_convert_w<<<3072, 256, 0, stream>>>(W_B, W_C, W_d, wcat);
    k_stoken<<<32, 256, 0, stream>>>(sq, W_st, b_st, stv);
    k_gemm<<<dim3(N_TOT / 128, M_TOT / 128), 256, 0, stream>>>(xb, wcat, g3);
    k_scan<1><<<512, 256, 0, stream>>>(x, g3, dp, Aar, b_B, b_C, b_d, stv, stb,
                                       nullptr, Pp, sEnd, nullptr);
    k_combine<<<32, 256, 0, stream>>>(Pp, sEnd, cin);
    k_scan<2><<<512, 256, 0, stream>>>(x, g3, dp, Aar, b_B, b_C, b_d, stv, stb,
                                       cin, nullptr, nullptr, out);
}

// Round 2
// 266.918 us; speedup vs baseline: 1.1259x; 1.1259x over previous
//
#include <hip/hip_runtime.h>
#include <hip/hip_bf16.h>
#include <cstdint>
#include <cstddef>

#define D_MODEL 1024
#define SEQ     2048
#define BATCH   8
#define M_TOT   (BATCH*SEQ)     // 16384
#define N_TOT   (3*D_MODEL)     // 3072
#define K_TOT   D_MODEL         // 1024
#define NCH     32              // scan chunks
#define LCH     (SEQ/NCH)       // 64 steps emitted per chunk
#define W_UP    16              // warmup steps (carry decays ~0.1^16)

typedef unsigned short u16;
typedef __attribute__((ext_vector_type(8))) short short8;
typedef __attribute__((ext_vector_type(4))) float f32x4;

__device__ __forceinline__ u16 f2bf(float f) {
    __hip_bfloat16 h = __float2bfloat16(f);   // RNE
    return __builtin_bit_cast(u16, h);
}
__device__ __forceinline__ float bf2f(u16 u) {
    __hip_bfloat16 h = __builtin_bit_cast(__hip_bfloat16, u);
    return __bfloat162float(h);
}
__device__ __forceinline__ float sigmoidf(float v) {
    return 1.0f / (1.0f + __expf(-v));
}
__device__ __forceinline__ void gld_lds16(const void* g, void* l) {
    __builtin_amdgcn_global_load_lds((const __attribute__((address_space(1))) void*)g,
                                     (__attribute__((address_space(3))) void*)l, 16, 0, 0);
}

// ---------------------------------------------------------------------------
// x (fp32) -> xb (bf16), fused with column-sum over L for the SToken mean.
// grid: 8 b * 4 dblk * 16 tblk = 512 blocks, 256 thr
__global__ void k_convert_x(const float* __restrict__ x, u16* __restrict__ xb,
                            float* __restrict__ sq) {
    int bid  = blockIdx.x;
    int tblk = bid & 15, dblk = (bid >> 4) & 3, b = bid >> 6;
    int d = dblk * 256 + threadIdx.x;
    size_t base = ((size_t)b * SEQ + (size_t)tblk * 128) * D_MODEL + d;
    float sum = 0.f;
    for (int t = 0; t < 128; ++t) {
        float v = x[base + (size_t)t * D_MODEL];
        sum += v;
        xb[base + (size_t)t * D_MODEL] = f2bf(v);
    }
    atomicAdd(&sq[b * D_MODEL + d], sum);
}

// W_B, W_C, W_d (fp32 [1024,1024]) -> wcat (bf16 [3072,1024])
__global__ void k_convert_w(const float* __restrict__ WB, const float* __restrict__ WC,
                            const float* __restrict__ Wd, u16* __restrict__ wcat) {
    int tg = blockIdx.x * 256 + threadIdx.x;
    size_t e0 = (size_t)tg * 4;
    int n = (int)(e0 >> 10), k0 = (int)(e0 & 1023);
    const float* W = (n < 1024) ? (WB + (size_t)n * 1024)
                   : (n < 2048) ? (WC + (size_t)(n - 1024) * 1024)
                                : (Wd + (size_t)(n - 2048) * 1024);
    float4 v = *(const float4*)&W[k0];
    wcat[e0 + 0] = f2bf(v.x);
    wcat[e0 + 1] = f2bf(v.y);
    wcat[e0 + 2] = f2bf(v.z);
    wcat[e0 + 3] = f2bf(v.w);
}

// stv[b,n] = sigmoid(relu( (sq[b,:]/L) @ W_st[n,:] + b_st[n] ))
__global__ void k_stoken(const float* __restrict__ sq, const float* __restrict__ Wst,
                         const float* __restrict__ bst, float* __restrict__ stv) {
    __shared__ float s[D_MODEL];
    int b = blockIdx.x >> 2, nblk = blockIdx.x & 3;
    for (int i = threadIdx.x; i < D_MODEL; i += 256)
        s[i] = sq[b * D_MODEL + i] * (1.0f / SEQ);
    __syncthreads();
    int n = nblk * 256 + threadIdx.x;
    const float* w = Wst + (size_t)n * D_MODEL;
    float acc = 0.f;
    for (int k = 0; k < D_MODEL; k += 4) {
        float4 wv = *(const float4*)&w[k];
        acc += s[k] * wv.x + s[k+1] * wv.y + s[k+2] * wv.z + s[k+3] * wv.w;
    }
    acc += bst[n];
    acc = fmaxf(acc, 0.f);
    stv[b * D_MODEL + n] = sigmoidf(acc);
}

// ---------------------------------------------------------------------------
// bf16 GEMM, B^T form: Cout[i,n] = sum_k A[i,k] * Bm[n,k].  m97 structure:
// 128x128 tile, BK=32, 4 waves (2x2), global_load_lds width 16, 2 barriers.
// 1-D grid + bijective XCD swizzle (3072 % 8 == 0); decompose so each XCD's
// chunk keeps a 0.79 MB B-panel L2-resident while streaming A.
__global__ __launch_bounds__(256) void k_gemm(const u16* __restrict__ A,
                                              const u16* __restrict__ Bm,
                                              u16* __restrict__ Cout) {
    __shared__ u16 lsA[128 * 32];
    __shared__ u16 lsB[128 * 32];
    const int tid = threadIdx.x;
    const int lane = tid & 63, wave = tid >> 6;
    const int wM = wave >> 1, wN = wave & 1;

    int wg  = blockIdx.x;
    int swz = (wg & 7) * (3072 / 8) + (wg >> 3);   // XCD-contiguous chunks
    const int i0 = (swz % 128) * 128;              // M tile (fast within chunk)
    const int n0 = (swz / 128) * 128;              // N tile
    const int r = lane & 15, g = lane >> 4;

    f32x4 acc[4][4] = {};

    for (int k0 = 0; k0 < K_TOT; k0 += 32) {
#pragma unroll
        for (int p = 0; p < 2; ++p) {
            int offBase = p * 4096 + wave * 1024;     // wave-uniform LDS byte base
            int off = offBase + lane * 16;
            int row = off >> 6;                       // 64 B per tile row (32 bf16)
            int cole = (off & 63) >> 1;
            gld_lds16(A + (size_t)(i0 + row) * K_TOT + k0 + cole, (char*)lsA + offBase);
            gld_lds16(Bm + (size_t)(n0 + row) * K_TOT + k0 + cole, (char*)lsB + offBase);
        }
        __syncthreads();

        short8 af[4], bfr[4];
#pragma unroll
        for (int m = 0; m < 4; ++m)
            af[m] = *(const short8*)&lsA[(wM * 64 + m * 16 + r) * 32 + g * 8];
#pragma unroll
        for (int n = 0; n < 4; ++n)
            bfr[n] = *(const short8*)&lsB[(wN * 64 + n * 16 + r) * 32 + g * 8];
#pragma unroll
        for (int m = 0; m < 4; ++m)
#pragma unroll
            for (int n = 0; n < 4; ++n)
                acc[m][n] = __builtin_amdgcn_mfma_f32_16x16x32_bf16(af[m], bfr[n], acc[m][n], 0, 0, 0);
        __syncthreads();
    }

    // epilogue: C/D layout col=lane&15, row=(lane>>4)*4+j  [HW-verified]
#pragma unroll
    for (int m = 0; m < 4; ++m)
#pragma unroll
        for (int n = 0; n < 4; ++n)
#pragma unroll
            for (int j = 0; j < 4; ++j) {
                size_t row = (size_t)(i0 + wM * 64 + m * 16 + g * 4 + j);
                size_t col = (size_t)(n0 + wN * 64 + n * 16 + r);
                Cout[row * N_TOT + col] = f2bf(acc[m][n][j]);
            }
}

// ---------------------------------------------------------------------------
// Single-pass chunked scan with warmup overlap.  |a_t| = sigmoid*|A| <~ 0.1,
// so a 16-step warmup bounds carry-truncation error by ~1e-16 — exact for
// chunk 0.  Each thread owns 2 d-channels (float2 / packed-bf16 loads).
// grid: 8 b * 32 chunks * 2 dblk = 512 blocks, 256 thr
__global__ void k_scan(const float* __restrict__ x, const u16* __restrict__ g3,
                       const float* __restrict__ dp, const float* __restrict__ Aar,
                       const float* __restrict__ bB, const float* __restrict__ bC,
                       const float* __restrict__ bd, const float* __restrict__ stv,
                       const float* __restrict__ stb, float* __restrict__ out) {
    int bid = blockIdx.x;
    int dblk = bid & 1, c = (bid >> 1) & (NCH - 1), b = bid >> 6;
    int d = dblk * 512 + threadIdx.x * 2;

    float2 bBv = *(const float2*)&bB[d];
    float2 bdv = *(const float2*)&bd[d];
    float2 bCv = *(const float2*)&bC[d];
    float2 stvv = *(const float2*)&stv[b * D_MODEL + d];
    float2 stbv = *(const float2*)&stb[d];
    float tc0 = stvv.x + stbv.x, tc1 = stvv.y + stbv.y;

    int t0 = c * LCH;
    int tw = (c == 0) ? 0 : t0 - W_UP;
    float s0 = 0.f, s1 = 0.f;

    size_t xoff = ((size_t)b * SEQ + tw) * D_MODEL + d;
    size_t goff = ((size_t)b * SEQ + tw) * N_TOT + d;
    size_t poff = (size_t)tw * D_MODEL + d;

    // warmup: recurrence only, no C-column read, no output
    for (int t = tw; t < t0; ++t) {
        float2 xv = *(const float2*)&x[xoff];
        uint gB = *(const uint*)&g3[goff];
        uint gd = *(const uint*)&g3[goff + 2048];
        float2 dpv = *(const float2*)&dp[poff];
        float2 Av  = *(const float2*)&Aar[poff];
        float b00 = bf2f((u16)(gB & 0xffff)) + bBv.x;
        float b01 = bf2f((u16)(gB >> 16)) + bBv.y;
        float de0 = sigmoidf(bf2f((u16)(gd & 0xffff)) + bdv.x + dpv.x);
        float de1 = sigmoidf(bf2f((u16)(gd >> 16)) + bdv.y + dpv.y);
        s0 = de0 * Av.x * s0 + de0 * b00 * xv.x;
        s1 = de1 * Av.y * s1 + de1 * b01 * xv.y;
        xoff += D_MODEL; goff += N_TOT; poff += D_MODEL;
    }
    // main: emit output
    for (int t = t0; t < t0 + LCH; ++t) {
        float2 xv = *(const float2*)&x[xoff];
        uint gB = *(const uint*)&g3[goff];
        uint gC = *(const uint*)&g3[goff + 1024];
        uint gd = *(const uint*)&g3[goff + 2048];
        float2 dpv = *(const float2*)&dp[poff];
        float2 Av  = *(const float2*)&Aar[poff];
        float b00 = bf2f((u16)(gB & 0xffff)) + bBv.x;
        float b01 = bf2f((u16)(gB >> 16)) + bBv.y;
        float de0 = sigmoidf(bf2f((u16)(gd & 0xffff)) + bdv.x + dpv.x);
        float de1 = sigmoidf(bf2f((u16)(gd >> 16)) + bdv.y + dpv.y);
        s0 = de0 * Av.x * s0 + de0 * b00 * xv.x;
        s1 = de1 * Av.y * s1 + de1 * b01 * xv.y;
        float c0 = bf2f((u16)(gC & 0xffff)) + bCv.x;
        float c1 = bf2f((u16)(gC >> 16)) + bCv.y;
        float y0 = (c0 * s0 + tc0 * xv.x) * sigmoidf(xv.x);
        float y1 = (c1 * s1 + tc1 * xv.y) * sigmoidf(xv.y);
        *(float2*)&out[xoff] = make_float2(y0, y1);
        xoff += D_MODEL; goff += N_TOT; poff += D_MODEL;
    }
}

// ---------------------------------------------------------------------------
extern "C" void kernel_launch(void* const* d_in, const int* in_sizes, int n_in,
                              void* d_out, int out_size, void* d_ws, size_t ws_size,
                              hipStream_t stream) {
    const float* x    = (const float*)d_in[0];
    const float* W_B  = (const float*)d_in[1];
    const float* b_B  = (const float*)d_in[2];
    const float* W_C  = (const float*)d_in[3];
    const float* b_C  = (const float*)d_in[4];
    const float* W_d  = (const float*)d_in[5];
    const float* b_d  = (const float*)d_in[6];
    const float* dp   = (const float*)d_in[7];
    const float* Aar  = (const float*)d_in[8];
    const float* W_st = (const float*)d_in[9];
    const float* b_st = (const float*)d_in[10];
    const float* stb  = (const float*)d_in[11];
    float* out = (float*)d_out;

    char* ws = (char*)d_ws;
    u16* xb   = (u16*)ws;  ws += (size_t)M_TOT * K_TOT * 2;   // 33.5 MB
    u16* wcat = (u16*)ws;  ws += (size_t)N_TOT * K_TOT * 2;   //  6.3 MB
    u16* g3   = (u16*)ws;  ws += (size_t)M_TOT * N_TOT * 2;   // 100.7 MB
    float* sq   = (float*)ws; ws += (size_t)BATCH * D_MODEL * 4;
    float* stv  = (float*)ws; ws += (size_t)BATCH * D_MODEL * 4;

    hipMemsetAsync(sq, 0, (size_t)BATCH * D_MODEL * 4, stream);
    k_convert_x<<<512, 256, 0, stream>>>(x, xb, sq);
    k_convert_w<<<3072, 256, 0, stream>>>(W_B, W_C, W_d, wcat);
    k_stoken<<<32, 256, 0, stream>>>(sq, W_st, b_st, stv);
    k_gemm<<<3072, 256, 0, stream>>>(xb, wcat, g3);
    k_scan<<<512, 256, 0, stream>>>(x, g3, dp, Aar, b_B, b_C, b_d, stv, stb, out);
}

// Round 3
// 242.568 us; speedup vs baseline: 1.2390x; 1.1004x over previous
//
#include <hip/hip_runtime.h>
#include <hip/hip_bf16.h>
#include <cstdint>
#include <cstddef>

#define D_MODEL 1024
#define SEQ     2048
#define BATCH   8
#define M_TOT   (BATCH*SEQ)     // 16384
#define N_TOT   (3*D_MODEL)     // 3072
#define K_TOT   D_MODEL         // 1024
#define KTILES  (K_TOT/64)      // 16
#define NCH     32              // scan chunks
#define LCH     (SEQ/NCH)       // 64 steps emitted per chunk
#define W_UP    16              // warmup steps (carry decays ~0.1^16)

typedef unsigned short u16;
typedef __attribute__((ext_vector_type(8))) short short8;
typedef __attribute__((ext_vector_type(4))) float f32x4;

__device__ __forceinline__ u16 f2bf(float f) {
    __hip_bfloat16 h = __float2bfloat16(f);   // RNE
    return __builtin_bit_cast(u16, h);
}
__device__ __forceinline__ float bf2f(u16 u) {
    __hip_bfloat16 h = __builtin_bit_cast(__hip_bfloat16, u);
    return __bfloat162float(h);
}
__device__ __forceinline__ float sigmoidf(float v) {
    return 1.0f / (1.0f + __expf(-v));
}
__device__ __forceinline__ void gld_lds16(const void* g, void* l) {
    __builtin_amdgcn_global_load_lds((const __attribute__((address_space(1))) void*)g,
                                     (__attribute__((address_space(3))) void*)l, 16, 0, 0);
}
// raw barrier with compiler-level memory fence (NOT __syncthreads: that drains vmcnt(0))
__device__ __forceinline__ void wg_barrier() {
    asm volatile("" ::: "memory");
    __builtin_amdgcn_s_barrier();
    asm volatile("" ::: "memory");
}

// ---------------------------------------------------------------------------
// x (fp32) -> xb (bf16), fused with column-sum over L for the SToken mean.
__global__ void k_convert_x(const float* __restrict__ x, u16* __restrict__ xb,
                            float* __restrict__ sq) {
    int bid  = blockIdx.x;
    int tblk = bid & 15, dblk = (bid >> 4) & 3, b = bid >> 6;
    int d = dblk * 256 + threadIdx.x;
    size_t base = ((size_t)b * SEQ + (size_t)tblk * 128) * D_MODEL + d;
    float sum = 0.f;
    for (int t = 0; t < 128; ++t) {
        float v = x[base + (size_t)t * D_MODEL];
        sum += v;
        xb[base + (size_t)t * D_MODEL] = f2bf(v);
    }
    atomicAdd(&sq[b * D_MODEL + d], sum);
}

// W_B, W_C, W_d (fp32 [1024,1024]) -> wcat (bf16 [3072,1024])
__global__ void k_convert_w(const float* __restrict__ WB, const float* __restrict__ WC,
                            const float* __restrict__ Wd, u16* __restrict__ wcat) {
    int tg = blockIdx.x * 256 + threadIdx.x;
    size_t e0 = (size_t)tg * 4;
    int n = (int)(e0 >> 10), k0 = (int)(e0 & 1023);
    const float* W = (n < 1024) ? (WB + (size_t)n * 1024)
                   : (n < 2048) ? (WC + (size_t)(n - 1024) * 1024)
                                : (Wd + (size_t)(n - 2048) * 1024);
    float4 v = *(const float4*)&W[k0];
    wcat[e0 + 0] = f2bf(v.x);
    wcat[e0 + 1] = f2bf(v.y);
    wcat[e0 + 2] = f2bf(v.z);
    wcat[e0 + 3] = f2bf(v.w);
}

// stv[b,n] = sigmoid(relu( (sq[b,:]/L) @ W_st[n,:] + b_st[n] ))
__global__ void k_stoken(const float* __restrict__ sq, const float* __restrict__ Wst,
                         const float* __restrict__ bst, float* __restrict__ stv) {
    __shared__ float s[D_MODEL];
    int b = blockIdx.x >> 2, nblk = blockIdx.x & 3;
    for (int i = threadIdx.x; i < D_MODEL; i += 256)
        s[i] = sq[b * D_MODEL + i] * (1.0f / SEQ);
    __syncthreads();
    int n = nblk * 256 + threadIdx.x;
    const float* w = Wst + (size_t)n * D_MODEL;
    float acc = 0.f;
    for (int k = 0; k < D_MODEL; k += 4) {
        float4 wv = *(const float4*)&w[k];
        acc += s[k] * wv.x + s[k+1] * wv.y + s[k+2] * wv.z + s[k+3] * wv.w;
    }
    acc += bst[n];
    acc = fmaxf(acc, 0.f);
    stv[b * D_MODEL + n] = sigmoidf(acc);
}

// ---------------------------------------------------------------------------
// 256x256-tile 8-phase bf16 GEMM (B^T form), plain-HIP port of the m201
// template: T2 LDS swizzle + T3 phase interleave + T4 counted vmcnt + T5
// setprio.  512 thr / 8 waves (2M x 4N); BK=64 as 2 K-slabs of 32; LDS
// 128 KiB = 2 buffers x {A,B} x 2 slabs of [256][32] bf16 (16 KiB each).
//
// Slab swizzle (involution, 16B-slot granular):  p ^= ((p>>7)&3)<<4
// Applied as pre-swizzled GLOBAL source for global_load_lds (linear LDS
// dest per rule #21) and swizzled ds_read address.  Makes the 16-row
// column-slice frag read bank-conflict-free.
//
// Schedule per K-tile t (buf = t&1), 4 phases, quadrant = (m-half, kk):
//   q0: read A(kk0,lo)+B(kk0) [8 rds]; stage {A1,B1}(t+1)->buf^1; vmcnt(8); bar; 16 MFMA; bar
//   q1: read A(kk1,lo)+B(kk1) [8 rds];                            bar; 16 MFMA; bar
//   q2: read A(kk0,hi) [4 rds, B reused];                         bar; 16 MFMA; bar
//   q3: read A(kk1,hi) [4 rds]; stage {A0,B0}(t+2)->buf; vmcnt(8); bar; 16 MFMA; bar
// vmcnt ledger: stage events are 4-load {A,B}-slab pairs; vmcnt(8) before a
// barrier forces the pair needed after that barrier to have landed while
// keeping 2 pairs in flight (never drains to 0 until the peeled tail).
// Cross-wave safety: vmcnt -> barrier -> read (vmcnt is per-wave; the
// barrier publishes it).  Every stage target slot's last reader finished
// >=1 barrier before the stage issue (checked per slab).
// ---------------------------------------------------------------------------
__device__ __forceinline__ u16* slab_ptr(u16* ls, int buf, int ab, int kk) {
    return ls + (size_t)((((buf << 1) | ab) << 1) | kk) * 8192;
}

__device__ __forceinline__ short8 ldsfrag(const u16* slab, int R, int g) {
    int off = R * 64 + ((g ^ ((R >> 1) & 3)) << 4);   // bytes, swizzled
    return *(const short8*)((const char*)slab + off);
}

__device__ __forceinline__ void stage2(const u16* __restrict__ A, const u16* __restrict__ Bm,
                                       u16* ls, int buf, int kk, int ktile,
                                       int i0, int n0, int w, int l) {
    // stages A-slab(kk) and B-slab(kk) of K-tile `ktile` into `buf`.
    // 4 gload_lds per wave; 8 waves cover the 2x16 KiB.
    int srow = l >> 2;                                // 0..15
    int scol = ((l & 3) ^ ((l >> 3) & 3)) << 4;       // pre-swizzled source byte
    int kbyte = (ktile * 64 + kk * 32) * 2;
    u16* la = slab_ptr(ls, buf, 0, kk);
    u16* lb = slab_ptr(ls, buf, 1, kk);
#pragma unroll
    for (int j = 0; j < 2; ++j) {
        int s = 2 * w + j;                            // slice 0..15 (1 KiB each)
        int row = s * 16 + srow;
        gld_lds16((const char*)(A  + (size_t)(i0 + row) * K_TOT) + kbyte + scol,
                  (char*)la + s * 1024);
        gld_lds16((const char*)(Bm + (size_t)(n0 + row) * K_TOT) + kbyte + scol,
                  (char*)lb + s * 1024);
    }
}

template<int VMQ0, int VMQ3, bool SG0, bool SG3>
__device__ __forceinline__ void kgroup(const u16* __restrict__ A, const u16* __restrict__ Bm,
                                       u16* ls, int t, int i0, int n0,
                                       int wM, int wN, int w, int l, int r, int g,
                                       f32x4 acc[8][4]) {
    const int buf = t & 1;
    const int RA = wM * 128 + r;
    const int RB = wN * 64 + r;
    short8 a[4], b0[4], b1[4];

    // ---- q0: kk=0, m-half 0
    {
        const u16* As = slab_ptr(ls, buf, 0, 0);
        const u16* Bs = slab_ptr(ls, buf, 1, 0);
#pragma unroll
        for (int m = 0; m < 4; ++m) a[m] = ldsfrag(As, RA + m * 16, g);
#pragma unroll
        for (int n = 0; n < 4; ++n) b0[n] = ldsfrag(Bs, RB + n * 16, g);
    }
    if (SG0) stage2(A, Bm, ls, buf ^ 1, 1, t + 1, i0, n0, w, l);
    if (VMQ0 >= 0) asm volatile("s_waitcnt vmcnt(%0)" :: "n"(VMQ0) : "memory");
    wg_barrier();
    __builtin_amdgcn_s_setprio(1);
#pragma unroll
    for (int m = 0; m < 4; ++m)
#pragma unroll
        for (int n = 0; n < 4; ++n)
            acc[m][n] = __builtin_amdgcn_mfma_f32_16x16x32_bf16(a[m], b0[n], acc[m][n], 0, 0, 0);
    __builtin_amdgcn_s_setprio(0);
    wg_barrier();

    // ---- q1: kk=1, m-half 0
    {
        const u16* As = slab_ptr(ls, buf, 0, 1);
        const u16* Bs = slab_ptr(ls, buf, 1, 1);
#pragma unroll
        for (int m = 0; m < 4; ++m) a[m] = ldsfrag(As, RA + m * 16, g);
#pragma unroll
        for (int n = 0; n < 4; ++n) b1[n] = ldsfrag(Bs, RB + n * 16, g);
    }
    wg_barrier();
    __builtin_amdgcn_s_setprio(1);
#pragma unroll
    for (int m = 0; m < 4; ++m)
#pragma unroll
        for (int n = 0; n < 4; ++n)
            acc[m][n] = __builtin_amdgcn_mfma_f32_16x16x32_bf16(a[m], b1[n], acc[m][n], 0, 0, 0);
    __builtin_amdgcn_s_setprio(0);
    wg_barrier();

    // ---- q2: kk=0, m-half 1 (B kk=0 frags reused)
    {
        const u16* As = slab_ptr(ls, buf, 0, 0);
#pragma unroll
        for (int m = 0; m < 4; ++m) a[m] = ldsfrag(As, RA + 64 + m * 16, g);
    }
    wg_barrier();
    __builtin_amdgcn_s_setprio(1);
#pragma unroll
    for (int m = 0; m < 4; ++m)
#pragma unroll
        for (int n = 0; n < 4; ++n)
            acc[4 + m][n] = __builtin_amdgcn_mfma_f32_16x16x32_bf16(a[m], b0[n], acc[4 + m][n], 0, 0, 0);
    __builtin_amdgcn_s_setprio(0);
    wg_barrier();

    // ---- q3: kk=1, m-half 1 (B kk=1 frags reused)
    {
        const u16* As = slab_ptr(ls, buf, 0, 1);
#pragma unroll
        for (int m = 0; m < 4; ++m) a[m] = ldsfrag(As, RA + 64 + m * 16, g);
    }
    if (SG3) stage2(A, Bm, ls, buf, 0, t + 2, i0, n0, w, l);
    if (VMQ3 >= 0) asm volatile("s_waitcnt vmcnt(%0)" :: "n"(VMQ3) : "memory");
    wg_barrier();
    __builtin_amdgcn_s_setprio(1);
#pragma unroll
    for (int m = 0; m < 4; ++m)
#pragma unroll
        for (int n = 0; n < 4; ++n)
            acc[4 + m][n] = __builtin_amdgcn_mfma_f32_16x16x32_bf16(a[m], b1[n], acc[4 + m][n], 0, 0, 0);
    __builtin_amdgcn_s_setprio(0);
    wg_barrier();
}

__global__ __launch_bounds__(512, 2) void k_gemm(const u16* __restrict__ A,
                                                 const u16* __restrict__ Bm,
                                                 u16* __restrict__ Cout) {
    __shared__ u16 ls[8 * 8192];   // 128 KiB
    const int tid = threadIdx.x;
    const int l = tid & 63, w = tid >> 6;
    const int wM = w >> 2, wN = w & 3;
    const int r = l & 15, g = l >> 4;
    const int i0 = blockIdx.y * 256;
    const int n0 = blockIdx.x * 256;

    f32x4 acc[8][4] = {};

    // prologue: 3 slab-pairs in flight, then force the first pair + publish
    stage2(A, Bm, ls, 0, 0, 0, i0, n0, w, l);   // {A0,B0}(0) -> buf0
    stage2(A, Bm, ls, 0, 1, 0, i0, n0, w, l);   // {A1,B1}(0) -> buf0
    stage2(A, Bm, ls, 1, 0, 1, i0, n0, w, l);   // {A0,B0}(1) -> buf1
    asm volatile("s_waitcnt vmcnt(8)" ::: "memory");
    wg_barrier();

    for (int t = 0; t < KTILES - 2; ++t)        // t = 0..13, steady state
        kgroup<8, 8, true, true>(A, Bm, ls, t, i0, n0, wM, wN, w, l, r, g, acc);
    kgroup<8, 4, true,  false>(A, Bm, ls, KTILES - 2, i0, n0, wM, wN, w, l, r, g, acc);
    kgroup<0, -1, false, false>(A, Bm, ls, KTILES - 1, i0, n0, wM, wN, w, l, r, g, acc);

    // epilogue: C/D layout col=lane&15, row=(lane>>4)*4+j  [HW-verified]
#pragma unroll
    for (int mi = 0; mi < 8; ++mi)
#pragma unroll
        for (int n = 0; n < 4; ++n)
#pragma unroll
            for (int j = 0; j < 4; ++j) {
                size_t row = (size_t)(i0 + wM * 128 + mi * 16 + g * 4 + j);
                size_t col = (size_t)(n0 + wN * 64 + n * 16 + r);
                Cout[row * N_TOT + col] = f2bf(acc[mi][n][j]);
            }
}

// ---------------------------------------------------------------------------
// Single-pass chunked scan with warmup overlap.  |a_t| = sigmoid*|A| <~ 0.1,
// so a 16-step warmup bounds carry-truncation error by ~1e-16 — exact for
// chunk 0.  Each thread owns 2 d-channels (float2 / packed-bf16 loads).
__global__ void k_scan(const float* __restrict__ x, const u16* __restrict__ g3,
                       const float* __restrict__ dp, const float* __restrict__ Aar,
                       const float* __restrict__ bB, const float* __restrict__ bC,
                       const float* __restrict__ bd, const float* __restrict__ stv,
                       const float* __restrict__ stb, float* __restrict__ out) {
    int bid = blockIdx.x;
    int dblk = bid & 1, c = (bid >> 1) & (NCH - 1), b = bid >> 6;
    int d = dblk * 512 + threadIdx.x * 2;

    float2 bBv = *(const float2*)&bB[d];
    float2 bdv = *(const float2*)&bd[d];
    float2 bCv = *(const float2*)&bC[d];
    float2 stvv = *(const float2*)&stv[b * D_MODEL + d];
    float2 stbv = *(const float2*)&stb[d];
    float tc0 = stvv.x + stbv.x, tc1 = stvv.y + stbv.y;

    int t0 = c * LCH;
    int tw = (c == 0) ? 0 : t0 - W_UP;
    float s0 = 0.f, s1 = 0.f;

    size_t xoff = ((size_t)b * SEQ + tw) * D_MODEL + d;
    size_t goff = ((size_t)b * SEQ + tw) * N_TOT + d;
    size_t poff = (size_t)tw * D_MODEL + d;

    for (int t = tw; t < t0; ++t) {
        float2 xv = *(const float2*)&x[xoff];
        uint gB = *(const uint*)&g3[goff];
        uint gd = *(const uint*)&g3[goff + 2048];
        float2 dpv = *(const float2*)&dp[poff];
        float2 Av  = *(const float2*)&Aar[poff];
        float b00 = bf2f((u16)(gB & 0xffff)) + bBv.x;
        float b01 = bf2f((u16)(gB >> 16)) + bBv.y;
        float de0 = sigmoidf(bf2f((u16)(gd & 0xffff)) + bdv.x + dpv.x);
        float de1 = sigmoidf(bf2f((u16)(gd >> 16)) + bdv.y + dpv.y);
        s0 = de0 * Av.x * s0 + de0 * b00 * xv.x;
        s1 = de1 * Av.y * s1 + de1 * b01 * xv.y;
        xoff += D_MODEL; goff += N_TOT; poff += D_MODEL;
    }
    for (int t = t0; t < t0 + LCH; ++t) {
        float2 xv = *(const float2*)&x[xoff];
        uint gB = *(const uint*)&g3[goff];
        uint gC = *(const uint*)&g3[goff + 1024];
        uint gd = *(const uint*)&g3[goff + 2048];
        float2 dpv = *(const float2*)&dp[poff];
        float2 Av  = *(const float2*)&Aar[poff];
        float b00 = bf2f((u16)(gB & 0xffff)) + bBv.x;
        float b01 = bf2f((u16)(gB >> 16)) + bBv.y;
        float de0 = sigmoidf(bf2f((u16)(gd & 0xffff)) + bdv.x + dpv.x);
        float de1 = sigmoidf(bf2f((u16)(gd >> 16)) + bdv.y + dpv.y);
        s0 = de0 * Av.x * s0 + de0 * b00 * xv.x;
        s1 = de1 * Av.y * s1 + de1 * b01 * xv.y;
        float c0 = bf2f((u16)(gC & 0xffff)) + bCv.x;
        float c1 = bf2f((u16)(gC >> 16)) + bCv.y;
        float y0 = (c0 * s0 + tc0 * xv.x) * sigmoidf(xv.x);
        float y1 = (c1 * s1 + tc1 * xv.y) * sigmoidf(xv.y);
        *(float2*)&out[xoff] = make_float2(y0, y1);
        xoff += D_MODEL; goff += N_TOT; poff += D_MODEL;
    }
}

// ---------------------------------------------------------------------------
extern "C" void kernel_launch(void* const* d_in, const int* in_sizes, int n_in,
                              void* d_out, int out_size, void* d_ws, size_t ws_size,
                              hipStream_t stream) {
    const float* x    = (const float*)d_in[0];
    const float* W_B  = (const float*)d_in[1];
    const float* b_B  = (const float*)d_in[2];
    const float* W_C  = (const float*)d_in[3];
    const float* b_C  = (const float*)d_in[4];
    const float* W_d  = (const float*)d_in[5];
    const float* b_d  = (const float*)d_in[6];
    const float* dp   = (const float*)d_in[7];
    const float* Aar  = (const float*)d_in[8];
    const float* W_st = (const float*)d_in[9];
    const float* b_st = (const float*)d_in[10];
    const float* stb  = (const float*)d_in[11];
    float* out = (float*)d_out;

    char* ws = (char*)d_ws;
    u16* xb   = (u16*)ws;  ws += (size_t)M_TOT * K_TOT * 2;   // 33.5 MB
    u16* wcat = (u16*)ws;  ws += (size_t)N_TOT * K_TOT * 2;   //  6.3 MB
    u16* g3   = (u16*)ws;  ws += (size_t)M_TOT * N_TOT * 2;   // 100.7 MB
    float* sq   = (float*)ws; ws += (size_t)BATCH * D_MODEL * 4;
    float* stv  = (float*)ws; ws += (size_t)BATCH * D_MODEL * 4;

    hipMemsetAsync(sq, 0, (size_t)BATCH * D_MODEL * 4, stream);
    k_convert_x<<<512, 256, 0, stream>>>(x, xb, sq);
    k_convert_w<<<3072, 256, 0, stream>>>(W_B, W_C, W_d, wcat);
    k_stoken<<<32, 256, 0, stream>>>(sq, W_st, b_st, stv);
    k_gemm<<<dim3(N_TOT / 256, M_TOT / 256), 512, 0, stream>>>(xb, wcat, g3);
    k_scan<<<512, 256, 0, stream>>>(x, g3, dp, Aar, b_B, b_C, b_d, stv, stb, out);
}

// Round 4
// 234.756 us; speedup vs baseline: 1.2802x; 1.0333x over previous
//
#include <hip/hip_runtime.h>
#include <hip/hip_bf16.h>
#include <cstdint>
#include <cstddef>

#define D_MODEL 1024
#define SEQ     2048
#define BATCH   8
#define M_TOT   (BATCH*SEQ)     // 16384
#define N_TOT   (3*D_MODEL)     // 3072
#define K_TOT   D_MODEL         // 1024
#define KTILES  (K_TOT/64)      // 16
#define NCH     32              // scan chunks
#define LCH     (SEQ/NCH)       // 64 steps emitted per chunk
#define W_UP    16              // warmup steps (carry decays ~0.1^16)

typedef unsigned short u16;
typedef __attribute__((ext_vector_type(8))) short short8;
typedef __attribute__((ext_vector_type(4))) float f32x4;

__device__ __forceinline__ u16 f2bf(float f) {
    __hip_bfloat16 h = __float2bfloat16(f);   // RNE
    return __builtin_bit_cast(u16, h);
}
__device__ __forceinline__ float bf2f(u16 u) {
    __hip_bfloat16 h = __builtin_bit_cast(__hip_bfloat16, u);
    return __bfloat162float(h);
}
__device__ __forceinline__ float sigmoidf(float v) {
    return 1.0f / (1.0f + __expf(-v));
}
__device__ __forceinline__ void gld_lds16(const void* g, void* l) {
    __builtin_amdgcn_global_load_lds((const __attribute__((address_space(1))) void*)g,
                                     (__attribute__((address_space(3))) void*)l, 16, 0, 0);
}
// raw barrier with compiler-level memory fence (NOT __syncthreads: that drains vmcnt(0))
__device__ __forceinline__ void wg_barrier() {
    asm volatile("" ::: "memory");
    __builtin_amdgcn_s_barrier();
    asm volatile("" ::: "memory");
}

// ---------------------------------------------------------------------------
// Merged converts: blocks 0..511  : x (fp32)->xb (bf16) + column-sum for SToken
//                  blocks 512..3583: W_B|W_C|W_d (fp32)->wcat (bf16 [3072,1024])
__global__ void k_convert(const float* __restrict__ x, u16* __restrict__ xb,
                          float* __restrict__ sq,
                          const float* __restrict__ WB, const float* __restrict__ WC,
                          const float* __restrict__ Wd, u16* __restrict__ wcat) {
    int bid = blockIdx.x;
    if (bid < 512) {
        int tblk = bid & 15, dblk = (bid >> 4) & 3, b = bid >> 6;
        int d = dblk * 256 + threadIdx.x;
        size_t base = ((size_t)b * SEQ + (size_t)tblk * 128) * D_MODEL + d;
        float sum = 0.f;
        for (int t = 0; t < 128; ++t) {
            float v = x[base + (size_t)t * D_MODEL];
            sum += v;
            xb[base + (size_t)t * D_MODEL] = f2bf(v);
        }
        atomicAdd(&sq[b * D_MODEL + d], sum);
    } else {
        int tg = (bid - 512) * 256 + threadIdx.x;
        size_t e0 = (size_t)tg * 4;
        int n = (int)(e0 >> 10), k0 = (int)(e0 & 1023);
        const float* W = (n < 1024) ? (WB + (size_t)n * 1024)
                       : (n < 2048) ? (WC + (size_t)(n - 1024) * 1024)
                                    : (Wd + (size_t)(n - 2048) * 1024);
        float4 v = *(const float4*)&W[k0];
        wcat[e0 + 0] = f2bf(v.x);
        wcat[e0 + 1] = f2bf(v.y);
        wcat[e0 + 2] = f2bf(v.z);
        wcat[e0 + 3] = f2bf(v.w);
    }
}

// stv[b,n] = sigmoid(relu( (sq[b,:]/L) @ W_st[n,:] + b_st[n] ))
__global__ void k_stoken(const float* __restrict__ sq, const float* __restrict__ Wst,
                         const float* __restrict__ bst, float* __restrict__ stv) {
    __shared__ float s[D_MODEL];
    int b = blockIdx.x >> 2, nblk = blockIdx.x & 3;
    for (int i = threadIdx.x; i < D_MODEL; i += 256)
        s[i] = sq[b * D_MODEL + i] * (1.0f / SEQ);
    __syncthreads();
    int n = nblk * 256 + threadIdx.x;
    const float* w = Wst + (size_t)n * D_MODEL;
    float acc = 0.f;
    for (int k = 0; k < D_MODEL; k += 4) {
        float4 wv = *(const float4*)&w[k];
        acc += s[k] * wv.x + s[k+1] * wv.y + s[k+2] * wv.z + s[k+3] * wv.w;
    }
    acc += bst[n];
    acc = fmaxf(acc, 0.f);
    stv[b * D_MODEL + n] = sigmoidf(acc);
}

// ---------------------------------------------------------------------------
// 256x256-tile bf16 GEMM (B^T form), de-phased K-loop: ONE barrier + ONE
// vmcnt(0) per K-tile; whole next tile staged into buf^1 right after the
// barrier (issue->wait window = full tile body >> HBM latency, so the
// vmcnt(0) drain is free); frag reads register-double-buffered and
// interleaved 1:1 with MFMA clusters so LDS-read time hides under MFMA.
//
// Safety: staging only ever targets buf^1; its last readers (tile t-1)
// are all behind barrier(t).  Reads of buf(t) need stage(t) complete:
// vmcnt(0) before barrier(t) forces each wave's DMA, barrier publishes.
// Slab swizzle (involution, 16B-slot):  p ^= ((p>>7)&3)<<4  — applied as
// pre-swizzled global source (linear LDS dest, rule #21) + swizzled ds_read.
// ---------------------------------------------------------------------------
__device__ __forceinline__ u16* slab_ptr(u16* ls, int buf, int ab, int kk) {
    return ls + (size_t)((((buf << 1) | ab) << 1) | kk) * 8192;
}

__device__ __forceinline__ short8 ldsfrag(const u16* slab, int R, int g) {
    int off = R * 64 + ((g ^ ((R >> 1) & 3)) << 4);   // bytes, swizzled
    return *(const short8*)((const char*)slab + off);
}

__device__ __forceinline__ void stage2(const u16* __restrict__ A, const u16* __restrict__ Bm,
                                       u16* ls, int buf, int kk, int ktile,
                                       int i0, int n0, int w, int l) {
    // stages A-slab(kk) and B-slab(kk) of K-tile `ktile` into `buf`.
    int srow = l >> 2;                                // 0..15
    int scol = ((l & 3) ^ ((l >> 3) & 3)) << 4;       // pre-swizzled source byte
    int kbyte = (ktile * 64 + kk * 32) * 2;
    u16* la = slab_ptr(ls, buf, 0, kk);
    u16* lb = slab_ptr(ls, buf, 1, kk);
#pragma unroll
    for (int j = 0; j < 2; ++j) {
        int s = 2 * w + j;                            // slice 0..15 (1 KiB each)
        int row = s * 16 + srow;
        gld_lds16((const char*)(A  + (size_t)(i0 + row) * K_TOT) + kbyte + scol,
                  (char*)la + s * 1024);
        gld_lds16((const char*)(Bm + (size_t)(n0 + row) * K_TOT) + kbyte + scol,
                  (char*)lb + s * 1024);
    }
}

template<bool SG>
__device__ __forceinline__ void kgroup(const u16* __restrict__ A, const u16* __restrict__ Bm,
                                       u16* ls, int t, int i0, int n0,
                                       int wM, int wN, int w, int l, int r, int g,
                                       f32x4 acc[8][4]) {
    const int buf = t & 1;
    const int RA = wM * 128 + r;
    const int RB = wN * 64 + r;

    asm volatile("s_waitcnt vmcnt(0)" ::: "memory");   // stage(t) done (queue cold)
    wg_barrier();                                      // publish; t-1 readers done
    if (SG) {
        stage2(A, Bm, ls, buf ^ 1, 0, t + 1, i0, n0, w, l);
        stage2(A, Bm, ls, buf ^ 1, 1, t + 1, i0, n0, w, l);
    }

    const u16* As0 = slab_ptr(ls, buf, 0, 0);
    const u16* Bs0 = slab_ptr(ls, buf, 1, 0);
    const u16* As1 = slab_ptr(ls, buf, 0, 1);
    const u16* Bs1 = slab_ptr(ls, buf, 1, 1);
    short8 a0[4], a1[4], b0[4], b1[4];

    // q0+q1 frag reads up front; q2/q3 A-reads interleave under MFMA clusters.
#pragma unroll
    for (int m = 0; m < 4; ++m) a0[m] = ldsfrag(As0, RA + m * 16, g);
#pragma unroll
    for (int n = 0; n < 4; ++n) b0[n] = ldsfrag(Bs0, RB + n * 16, g);
#pragma unroll
    for (int m = 0; m < 4; ++m) a1[m] = ldsfrag(As1, RA + m * 16, g);
#pragma unroll
    for (int n = 0; n < 4; ++n) b1[n] = ldsfrag(Bs1, RB + n * 16, g);

    __builtin_amdgcn_s_setprio(1);
#pragma unroll
    for (int m = 0; m < 4; ++m)
#pragma unroll
        for (int n = 0; n < 4; ++n)
            acc[m][n] = __builtin_amdgcn_mfma_f32_16x16x32_bf16(a0[m], b0[n], acc[m][n], 0, 0, 0);
    __builtin_amdgcn_s_setprio(0);

#pragma unroll
    for (int m = 0; m < 4; ++m) a0[m] = ldsfrag(As0, RA + 64 + m * 16, g);   // kk0 hi

    __builtin_amdgcn_s_setprio(1);
#pragma unroll
    for (int m = 0; m < 4; ++m)
#pragma unroll
        for (int n = 0; n < 4; ++n)
            acc[m][n] = __builtin_amdgcn_mfma_f32_16x16x32_bf16(a1[m], b1[n], acc[m][n], 0, 0, 0);
    __builtin_amdgcn_s_setprio(0);

#pragma unroll
    for (int m = 0; m < 4; ++m) a1[m] = ldsfrag(As1, RA + 64 + m * 16, g);   // kk1 hi

    __builtin_amdgcn_s_setprio(1);
#pragma unroll
    for (int m = 0; m < 4; ++m)
#pragma unroll
        for (int n = 0; n < 4; ++n)
            acc[4 + m][n] = __builtin_amdgcn_mfma_f32_16x16x32_bf16(a0[m], b0[n], acc[4 + m][n], 0, 0, 0);
#pragma unroll
    for (int m = 0; m < 4; ++m)
#pragma unroll
        for (int n = 0; n < 4; ++n)
            acc[4 + m][n] = __builtin_amdgcn_mfma_f32_16x16x32_bf16(a1[m], b1[n], acc[4 + m][n], 0, 0, 0);
    __builtin_amdgcn_s_setprio(0);
}

__global__ __launch_bounds__(512, 2) void k_gemm(const u16* __restrict__ A,
                                                 const u16* __restrict__ Bm,
                                                 u16* __restrict__ Cout) {
    __shared__ u16 ls[8 * 8192];   // 128 KiB
    const int tid = threadIdx.x;
    const int l = tid & 63, w = tid >> 6;
    const int wM = w >> 2, wN = w & 3;
    const int r = l & 15, g = l >> 4;
    const int i0 = blockIdx.y * 256;
    const int n0 = blockIdx.x * 256;

    f32x4 acc[8][4] = {};

    // prologue: stage tile 0 into buf0
    stage2(A, Bm, ls, 0, 0, 0, i0, n0, w, l);
    stage2(A, Bm, ls, 0, 1, 0, i0, n0, w, l);

    for (int t = 0; t < KTILES - 1; ++t)
        kgroup<true>(A, Bm, ls, t, i0, n0, wM, wN, w, l, r, g, acc);
    kgroup<false>(A, Bm, ls, KTILES - 1, i0, n0, wM, wN, w, l, r, g, acc);

    // epilogue: C/D layout col=lane&15, row=(lane>>4)*4+j  [HW-verified]
#pragma unroll
    for (int mi = 0; mi < 8; ++mi)
#pragma unroll
        for (int n = 0; n < 4; ++n)
#pragma unroll
            for (int j = 0; j < 4; ++j) {
                size_t row = (size_t)(i0 + wM * 128 + mi * 16 + g * 4 + j);
                size_t col = (size_t)(n0 + wN * 64 + n * 16 + r);
                Cout[row * N_TOT + col] = f2bf(acc[mi][n][j]);
            }
}

// ---------------------------------------------------------------------------
// Single-pass chunked scan with warmup overlap.  |a_t| = sigmoid*|A| <~ 0.1,
// so a 16-step warmup bounds carry-truncation error by ~1e-16 — exact for
// chunk 0.  Each thread owns 2 d-channels (float2 / packed-bf16 loads).
__global__ void k_scan(const float* __restrict__ x, const u16* __restrict__ g3,
                       const float* __restrict__ dp, const float* __restrict__ Aar,
                       const float* __restrict__ bB, const float* __restrict__ bC,
                       const float* __restrict__ bd, const float* __restrict__ stv,
                       const float* __restrict__ stb, float* __restrict__ out) {
    int bid = blockIdx.x;
    int dblk = bid & 1, c = (bid >> 1) & (NCH - 1), b = bid >> 6;
    int d = dblk * 512 + threadIdx.x * 2;

    float2 bBv = *(const float2*)&bB[d];
    float2 bdv = *(const float2*)&bd[d];
    float2 bCv = *(const float2*)&bC[d];
    float2 stvv = *(const float2*)&stv[b * D_MODEL + d];
    float2 stbv = *(const float2*)&stb[d];
    float tc0 = stvv.x + stbv.x, tc1 = stvv.y + stbv.y;

    int t0 = c * LCH;
    int tw = (c == 0) ? 0 : t0 - W_UP;
    float s0 = 0.f, s1 = 0.f;

    size_t xoff = ((size_t)b * SEQ + tw) * D_MODEL + d;
    size_t goff = ((size_t)b * SEQ + tw) * N_TOT + d;
    size_t poff = (size_t)tw * D_MODEL + d;

    for (int t = tw; t < t0; ++t) {
        float2 xv = *(const float2*)&x[xoff];
        uint gB = *(const uint*)&g3[goff];
        uint gd = *(const uint*)&g3[goff + 2048];
        float2 dpv = *(const float2*)&dp[poff];
        float2 Av  = *(const float2*)&Aar[poff];
        float b00 = bf2f((u16)(gB & 0xffff)) + bBv.x;
        float b01 = bf2f((u16)(gB >> 16)) + bBv.y;
        float de0 = sigmoidf(bf2f((u16)(gd & 0xffff)) + bdv.x + dpv.x);
        float de1 = sigmoidf(bf2f((u16)(gd >> 16)) + bdv.y + dpv.y);
        s0 = de0 * Av.x * s0 + de0 * b00 * xv.x;
        s1 = de1 * Av.y * s1 + de1 * b01 * xv.y;
        xoff += D_MODEL; goff += N_TOT; poff += D_MODEL;
    }
    for (int t = t0; t < t0 + LCH; ++t) {
        float2 xv = *(const float2*)&x[xoff];
        uint gB = *(const uint*)&g3[goff];
        uint gC = *(const uint*)&g3[goff + 1024];
        uint gd = *(const uint*)&g3[goff + 2048];
        float2 dpv = *(const float2*)&dp[poff];
        float2 Av  = *(const float2*)&Aar[poff];
        float b00 = bf2f((u16)(gB & 0xffff)) + bBv.x;
        float b01 = bf2f((u16)(gB >> 16)) + bBv.y;
        float de0 = sigmoidf(bf2f((u16)(gd & 0xffff)) + bdv.x + dpv.x);
        float de1 = sigmoidf(bf2f((u16)(gd >> 16)) + bdv.y + dpv.y);
        s0 = de0 * Av.x * s0 + de0 * b00 * xv.x;
        s1 = de1 * Av.y * s1 + de1 * b01 * xv.y;
        float c0 = bf2f((u16)(gC & 0xffff)) + bCv.x;
        float c1 = bf2f((u16)(gC >> 16)) + bCv.y;
        float y0 = (c0 * s0 + tc0 * xv.x) * sigmoidf(xv.x);
        float y1 = (c1 * s1 + tc1 * xv.y) * sigmoidf(xv.y);
        *(float2*)&out[xoff] = make_float2(y0, y1);
        xoff += D_MODEL; goff += N_TOT; poff += D_MODEL;
    }
}

// ---------------------------------------------------------------------------
extern "C" void kernel_launch(void* const* d_in, const int* in_sizes, int n_in,
                              void* d_out, int out_size, void* d_ws, size_t ws_size,
                              hipStream_t stream) {
    const float* x    = (const float*)d_in[0];
    const float* W_B  = (const float*)d_in[1];
    const float* b_B  = (const float*)d_in[2];
    const float* W_C  = (const float*)d_in[3];
    const float* b_C  = (const float*)d_in[4];
    const float* W_d  = (const float*)d_in[5];
    const float* b_d  = (const float*)d_in[6];
    const float* dp   = (const float*)d_in[7];
    const float* Aar  = (const float*)d_in[8];
    const float* W_st = (const float*)d_in[9];
    const float* b_st = (const float*)d_in[10];
    const float* stb  = (const float*)d_in[11];
    float* out = (float*)d_out;

    char* ws = (char*)d_ws;
    u16* xb   = (u16*)ws;  ws += (size_t)M_TOT * K_TOT * 2;   // 33.5 MB
    u16* wcat = (u16*)ws;  ws += (size_t)N_TOT * K_TOT * 2;   //  6.3 MB
    u16* g3   = (u16*)ws;  ws += (size_t)M_TOT * N_TOT * 2;   // 100.7 MB
    float* sq   = (float*)ws; ws += (size_t)BATCH * D_MODEL * 4;
    float* stv  = (float*)ws; ws += (size_t)BATCH * D_MODEL * 4;

    hipMemsetAsync(sq, 0, (size_t)BATCH * D_MODEL * 4, stream);
    k_convert<<<3584, 256, 0, stream>>>(x, xb, sq, W_B, W_C, W_d, wcat);
    k_stoken<<<32, 256, 0, stream>>>(sq, W_st, b_st, stv);
    k_gemm<<<dim3(N_TOT / 256, M_TOT / 256), 512, 0, stream>>>(xb, wcat, g3);
    k_scan<<<512, 256, 0, stream>>>(x, g3, dp, Aar, b_B, b_C, b_d, stv, stb, out);
}